// Round 2
// baseline (847.017 us; speedup 1.0000x reference)
//
#include <hip/hip_runtime.h>
#include <hip/hip_bf16.h>
#include <math.h>

// Problem constants (mirrors reference)
#define NFEAT 96
#define NHID  96
#define NCLASS 40

// ---------------------------------------------------------------------------
// Kernel 1: degree count. One thread per edge, atomicAdd on cnt[dst].
// ---------------------------------------------------------------------------
__global__ __launch_bounds__(256) void count_kernel(const int* __restrict__ ei,
                                                    float* __restrict__ cnt, int E) {
    int e = blockIdx.x * 256 + threadIdx.x;
    if (e < E) {
        int dst = ei[E + e];
        atomicAdd(&cnt[dst], 1.0f);
    }
}

// ---------------------------------------------------------------------------
// Kernel 2: scatter-add of feat[src] into agg[dst]. One thread per (edge,feat).
// Consecutive threads cover consecutive feats of one edge -> coalesced gather,
// and the 96 atomics per edge land in 2 consecutive cachelines.
// ---------------------------------------------------------------------------
__global__ __launch_bounds__(256) void scatter_kernel(const float* __restrict__ feat,
                                                      const int* __restrict__ ei,
                                                      float* __restrict__ agg, int E) {
    int idx = blockIdx.x * 256 + threadIdx.x;
    int total = E * NFEAT;
    if (idx >= total) return;
    int e = idx / NFEAT;
    int f = idx - e * NFEAT;
    int src = ei[e];
    int dst = ei[E + e];
    float v = feat[src * NFEAT + f];
    atomicAdd(&agg[dst * NFEAT + f], v);
}

// ---------------------------------------------------------------------------
// Kernel 3: layer-1 fused:  h = relu( (agg/max(cnt,1)) @ Wl^T + b + x @ Wr^T )
// Block = 256 threads, 8 nodes/block. Thread (nl = tid>>5, j0 = tid&31)
// computes outputs j0, j0+32, j0+64 for node nl. W tiles staged in LDS with
// +1 row padding (stride 33) so lane-j access (j*33+k)%32 = (j+k)%32 is
// conflict-free.
// ---------------------------------------------------------------------------
__global__ __launch_bounds__(256) void l1_kernel(const float* __restrict__ x,
                                                 const float* __restrict__ agg,
                                                 const float* __restrict__ cnt,
                                                 const float* __restrict__ Wl,
                                                 const float* __restrict__ b,
                                                 const float* __restrict__ Wr,
                                                 float* __restrict__ h, int N) {
    __shared__ float sWl[96 * 33];   // K-tile of 32, padded stride 33
    __shared__ float sWr[96 * 33];
    __shared__ float sA[8 * 96];     // pre-scaled agg
    __shared__ float sX[8 * 96];

    int tid  = threadIdx.x;
    int base = blockIdx.x * 8;

    // Stage the 8 nodes' agg (scaled) and x rows: 768 elements each, 3/thread.
    for (int t = 0; t < 3; ++t) {
        int flat = tid + t * 256;
        int n = flat / 96;
        int k = flat - n * 96;
        int node = base + n;
        float a = 0.f, xv = 0.f;
        if (node < N) {
            float inv = 1.0f / fmaxf(cnt[node], 1.0f);
            a  = agg[node * 96 + k] * inv;
            xv = x[node * 96 + k];
        }
        sA[flat] = a;
        sX[flat] = xv;
    }

    int nl = tid >> 5;     // node within block, 0..7
    int j0 = tid & 31;     // output feature base, 0..31
    float acc0 = 0.f, acc1 = 0.f, acc2 = 0.f;

    for (int kt = 0; kt < 3; ++kt) {
        __syncthreads();   // sA/sX visible (iter 0); previous W tile consumed (iter>0)
        // Load W tiles: 96x32 each = 3072 elements, 12/thread.
        for (int t = 0; t < 12; ++t) {
            int flat = tid + t * 256;
            int j  = flat >> 5;
            int kk = flat & 31;
            sWl[j * 33 + kk] = Wl[j * 96 + kt * 32 + kk];
            sWr[j * 33 + kk] = Wr[j * 96 + kt * 32 + kk];
        }
        __syncthreads();
        int kbase = kt * 32;
        #pragma unroll
        for (int kk = 0; kk < 32; ++kk) {
            float a  = sA[nl * 96 + kbase + kk];
            float xv = sX[nl * 96 + kbase + kk];
            acc0 += a * sWl[ j0       * 33 + kk] + xv * sWr[ j0       * 33 + kk];
            acc1 += a * sWl[(j0 + 32) * 33 + kk] + xv * sWr[(j0 + 32) * 33 + kk];
            acc2 += a * sWl[(j0 + 64) * 33 + kk] + xv * sWr[(j0 + 64) * 33 + kk];
        }
    }

    int node = base + nl;
    if (node < N) {
        h[node * 96 + j0     ] = fmaxf(acc0 + b[j0     ], 0.f);
        h[node * 96 + j0 + 32] = fmaxf(acc1 + b[j0 + 32], 0.f);
        h[node * 96 + j0 + 64] = fmaxf(acc2 + b[j0 + 64], 0.f);
    }
}

// ---------------------------------------------------------------------------
// Kernel 4: layer-2 fused:  o = log_softmax( (agg/max(cnt,1)) @ W2l^T + b2
//                                            + h @ W2r^T )
// Block = 256 threads = 4 waves; one wave per node; lane j<40 computes one
// class logit; wave shuffle reduction for max / logsumexp.
// ---------------------------------------------------------------------------
__global__ __launch_bounds__(256) void l2_kernel(const float* __restrict__ h,
                                                 const float* __restrict__ agg,
                                                 const float* __restrict__ cnt,
                                                 const float* __restrict__ Wl,
                                                 const float* __restrict__ b,
                                                 const float* __restrict__ Wr,
                                                 float* __restrict__ out, int N) {
    __shared__ float sWl[NCLASS * 97];   // padded stride 97: bank = (j+k)%32
    __shared__ float sWr[NCLASS * 97];
    __shared__ float sH[4 * 96];
    __shared__ float sA[4 * 96];

    int tid = threadIdx.x;
    // Stage weights: 40*96 = 3840 elements each, exactly 15/thread.
    for (int t = 0; t < 15; ++t) {
        int flat = tid + t * 256;
        int j = flat / 96;
        int k = flat - j * 96;
        sWl[j * 97 + k] = Wl[flat];
        sWr[j * 97 + k] = Wr[flat];
    }
    // Stage the 4 nodes' h and scaled agg rows (384 elements each).
    int base = blockIdx.x * 4;
    for (int t = 0; t < 2; ++t) {
        int flat = tid + t * 256;
        if (flat < 4 * 96) {
            int n = flat / 96;
            int k = flat - n * 96;
            int node = base + n;
            float hv = 0.f, av = 0.f;
            if (node < N) {
                float inv = 1.0f / fmaxf(cnt[node], 1.0f);
                hv = h[node * 96 + k];
                av = agg[node * 96 + k] * inv;
            }
            sH[flat] = hv;
            sA[flat] = av;
        }
    }
    __syncthreads();

    int w    = tid >> 6;    // wave id = node within block
    int lane = tid & 63;
    int node = base + w;

    float acc = -INFINITY;
    if (lane < NCLASS) {
        acc = b[lane];
        const float* wl = &sWl[lane * 97];
        const float* wr = &sWr[lane * 97];
        const float* ha = &sH[w * 96];
        const float* aa = &sA[w * 96];
        #pragma unroll 8
        for (int k = 0; k < 96; ++k) {
            acc += aa[k] * wl[k] + ha[k] * wr[k];
        }
    }

    // wave-wide max (idle lanes hold -inf)
    float m = acc;
    #pragma unroll
    for (int off = 32; off >= 1; off >>= 1)
        m = fmaxf(m, __shfl_xor(m, off));

    float e = (lane < NCLASS) ? __expf(acc - m) : 0.f;
    float s = e;
    #pragma unroll
    for (int off = 32; off >= 1; off >>= 1)
        s += __shfl_xor(s, off);

    if (node < N && lane < NCLASS) {
        out[node * NCLASS + lane] = acc - m - __logf(s);
    }
}

// ---------------------------------------------------------------------------
// Host launcher
// ---------------------------------------------------------------------------
extern "C" void kernel_launch(void* const* d_in, const int* in_sizes, int n_in,
                              void* d_out, int out_size, void* d_ws, size_t ws_size,
                              hipStream_t stream) {
    const float* x    = (const float*)d_in[0];
    const int*   ei   = (const int*)  d_in[1];
    const float* W1l  = (const float*)d_in[2];
    const float* b1   = (const float*)d_in[3];
    const float* W1r  = (const float*)d_in[4];
    const float* W2l  = (const float*)d_in[5];
    const float* b2   = (const float*)d_in[6];
    const float* W2r  = (const float*)d_in[7];
    float* out = (float*)d_out;

    const int N = in_sizes[0] / NFEAT;   // 50000
    const int E = in_sizes[1] / 2;       // 800000

    // Workspace layout (all float):
    //   cnt : N            (padded to 50176)
    //   agg : N*96         (reused for layer 1 and layer 2 aggregation)
    //   h   : N*96
    float* cnt = (float*)d_ws;
    float* agg = cnt + 50176;
    float* h   = agg + (size_t)N * NFEAT;

    // Zero cnt + agg (ws is poisoned 0xAA before every call).
    hipMemsetAsync(cnt, 0, sizeof(float) * 50176, stream);
    hipMemsetAsync(agg, 0, sizeof(float) * (size_t)N * NFEAT, stream);

    // Degree counts.
    count_kernel<<<(E + 255) / 256, 256, 0, stream>>>(ei, cnt, E);

    // Layer 1 scatter: agg += x[src]
    {
        int total = E * NFEAT;
        scatter_kernel<<<(total + 255) / 256, 256, 0, stream>>>(x, ei, agg, E);
    }

    // Layer 1 GEMM + bias + relu -> h
    l1_kernel<<<(N + 7) / 8, 256, 0, stream>>>(x, agg, cnt, W1l, b1, W1r, h, N);

    // Re-zero agg for layer 2.
    hipMemsetAsync(agg, 0, sizeof(float) * (size_t)N * NFEAT, stream);

    // Layer 2 scatter: agg += h[src]
    {
        int total = E * NFEAT;
        scatter_kernel<<<(total + 255) / 256, 256, 0, stream>>>(h, ei, agg, E);
    }

    // Layer 2 GEMM + bias + log_softmax -> out
    l2_kernel<<<(N + 3) / 4, 256, 0, stream>>>(h, agg, cnt, W2l, b2, W2r, out, N);
}

// Round 3
// 429.815 us; speedup vs baseline: 1.9707x; 1.9707x over previous
//
#include <hip/hip_runtime.h>
#include <hip/hip_bf16.h>
#include <math.h>

#define NFEAT 96
#define NCLASS 40

// ---------------------------------------------------------------------------
// CSR construction: histogram of dst -> exclusive prefix sum -> position fill.
// ---------------------------------------------------------------------------
__global__ __launch_bounds__(256) void hist_kernel(const int* __restrict__ ei,
                                                   int* __restrict__ cnt, int E) {
    int e = blockIdx.x * 256 + threadIdx.x;
    if (e < E) atomicAdd(&cnt[ei[E + e]], 1);
}

// Block scans 1024 elements (4/thread), writes block-local exclusive prefix
// and the block total.
__global__ __launch_bounds__(256) void scan1_kernel(const int* __restrict__ cnt,
                                                    int* __restrict__ rp,
                                                    int* __restrict__ bsum) {
    __shared__ int sdata[256];
    int tid  = threadIdx.x;
    int base = blockIdx.x * 1024 + tid * 4;
    int v0 = cnt[base], v1 = cnt[base + 1], v2 = cnt[base + 2], v3 = cnt[base + 3];
    int tsum = v0 + v1 + v2 + v3;
    sdata[tid] = tsum;
    __syncthreads();
    int mine = tsum;
    for (int off = 1; off < 256; off <<= 1) {
        int other = (tid >= off) ? sdata[tid - off] : 0;
        __syncthreads();
        mine += other;
        sdata[tid] = mine;
        __syncthreads();
    }
    int excl = mine - tsum;
    rp[base]     = excl;
    rp[base + 1] = excl + v0;
    rp[base + 2] = excl + v0 + v1;
    rp[base + 3] = excl + v0 + v1 + v2;
    if (tid == 255) bsum[blockIdx.x] = mine;
}

__global__ void scan2_kernel(int* __restrict__ bsum, int nb) {
    if (threadIdx.x == 0 && blockIdx.x == 0) {
        int acc = 0;
        for (int i = 0; i < nb; ++i) { int v = bsum[i]; bsum[i] = acc; acc += v; }
    }
}

__global__ __launch_bounds__(256) void scan3_kernel(int* __restrict__ rp,
                                                    const int* __restrict__ bsum,
                                                    int* __restrict__ fill) {
    int base = blockIdx.x * 1024 + threadIdx.x * 4;
    int off  = bsum[blockIdx.x];
    #pragma unroll
    for (int t = 0; t < 4; ++t) {
        int v = rp[base + t] + off;
        rp[base + t]   = v;
        fill[base + t] = v;
    }
}

__global__ __launch_bounds__(256) void fill_kernel(const int* __restrict__ ei,
                                                   int* __restrict__ fill,
                                                   int* __restrict__ col, int E) {
    int e = blockIdx.x * 256 + threadIdx.x;
    if (e < E) {
        int dst = ei[E + e];
        int src = ei[e];
        int pos = atomicAdd(&fill[dst], 1);
        col[pos] = src;
    }
}

// ---------------------------------------------------------------------------
// Layer-1 aggregation: gather-mean of x rows via CSR. Thread = (node, float4
// quarter-chunk q of the 96 feats). No atomics; coalesced 384 B per edge.
// ---------------------------------------------------------------------------
__global__ __launch_bounds__(256) void agg1_kernel(const float4* __restrict__ x4,
                                                   const int* __restrict__ rp,
                                                   const int* __restrict__ col,
                                                   float4* __restrict__ agg4, int N) {
    int idx = blockIdx.x * 256 + threadIdx.x;
    if (idx >= N * 24) return;
    int n = idx / 24;
    int q = idx - n * 24;
    int s = rp[n], e = rp[n + 1];
    float ax = 0.f, ay = 0.f, az = 0.f, aw = 0.f;
    int i = s;
    for (; i + 3 < e; i += 4) {
        int c0 = col[i], c1 = col[i + 1], c2 = col[i + 2], c3 = col[i + 3];
        float4 v0 = x4[c0 * 24 + q];
        float4 v1 = x4[c1 * 24 + q];
        float4 v2 = x4[c2 * 24 + q];
        float4 v3 = x4[c3 * 24 + q];
        ax += v0.x + v1.x + v2.x + v3.x;
        ay += v0.y + v1.y + v2.y + v3.y;
        az += v0.z + v1.z + v2.z + v3.z;
        aw += v0.w + v1.w + v2.w + v3.w;
    }
    for (; i < e; ++i) {
        float4 v = x4[col[i] * 24 + q];
        ax += v.x; ay += v.y; az += v.z; aw += v.w;
    }
    int deg = e - s;
    float inv = 1.0f / (float)(deg > 1 ? deg : 1);
    float4 r;
    r.x = ax * inv; r.y = ay * inv; r.z = az * inv; r.w = aw * inv;
    agg4[n * 24 + q] = r;
}

// ---------------------------------------------------------------------------
// Layer-1 fused GEMM: h = relu(agg @ Wl^T + b + x @ Wr^T).
// 32 nodes/block, 256 threads. j0=tid&31 covers outputs {j0,j0+32,j0+64};
// ng=tid>>5 covers nodes {ng,ng+8,ng+16,ng+24}. Weights K-tiled (32) into LDS
// with row stride 34 floats (2-way bank alias = free, 8B-aligned for float2).
// ---------------------------------------------------------------------------
__global__ __launch_bounds__(256) void l1_kernel(const float* __restrict__ x,
                                                 const float* __restrict__ agg,
                                                 const float* __restrict__ Wl,
                                                 const float* __restrict__ b,
                                                 const float* __restrict__ Wr,
                                                 float* __restrict__ h, int N) {
    __shared__ float sWl[96 * 34];
    __shared__ float sWr[96 * 34];
    __shared__ float sA[32 * 96];
    __shared__ float sX[32 * 96];
    int tid  = threadIdx.x;
    int base = blockIdx.x * 32;

    // Stage sA/sX: 32 nodes x 24 float4 = 768 f4 each, 3/thread.
    for (int t = 0; t < 3; ++t) {
        int flat = tid + t * 256;
        int n = flat / 24;
        int q = flat - 24 * n;
        int node = base + n;
        float4 a  = {0.f, 0.f, 0.f, 0.f};
        float4 xv = {0.f, 0.f, 0.f, 0.f};
        if (node < N) {
            a  = ((const float4*)agg)[node * 24 + q];
            xv = ((const float4*)x)[node * 24 + q];
        }
        *(float4*)&sA[n * 96 + 4 * q] = a;
        *(float4*)&sX[n * 96 + 4 * q] = xv;
    }

    int j0 = tid & 31;
    int ng = tid >> 5;
    float acc[4][3] = {};

    for (int kt = 0; kt < 3; ++kt) {
        __syncthreads();
        // Stage W tiles: 96 rows x 16 float2 each = 1536 f2, 6/thread each.
        for (int t = 0; t < 6; ++t) {
            int flat = tid + t * 256;
            int j  = flat >> 4;
            int kh = flat & 15;
            float2 wl = ((const float2*)Wl)[j * 48 + kt * 16 + kh];
            float2 wr = ((const float2*)Wr)[j * 48 + kt * 16 + kh];
            *(float2*)&sWl[j * 34 + 2 * kh] = wl;
            *(float2*)&sWr[j * 34 + 2 * kh] = wr;
        }
        __syncthreads();
        int kb = kt * 32;
        #pragma unroll
        for (int ks = 0; ks < 16; ++ks) {
            float2 wl0 = *(const float2*)&sWl[ j0       * 34 + 2 * ks];
            float2 wl1 = *(const float2*)&sWl[(j0 + 32) * 34 + 2 * ks];
            float2 wl2 = *(const float2*)&sWl[(j0 + 64) * 34 + 2 * ks];
            float2 wr0 = *(const float2*)&sWr[ j0       * 34 + 2 * ks];
            float2 wr1 = *(const float2*)&sWr[(j0 + 32) * 34 + 2 * ks];
            float2 wr2 = *(const float2*)&sWr[(j0 + 64) * 34 + 2 * ks];
            #pragma unroll
            for (int i = 0; i < 4; ++i) {
                int nl = ng + i * 8;
                float2 a  = *(const float2*)&sA[nl * 96 + kb + 2 * ks];
                float2 xv = *(const float2*)&sX[nl * 96 + kb + 2 * ks];
                acc[i][0] += a.x * wl0.x + a.y * wl0.y + xv.x * wr0.x + xv.y * wr0.y;
                acc[i][1] += a.x * wl1.x + a.y * wl1.y + xv.x * wr1.x + xv.y * wr1.y;
                acc[i][2] += a.x * wl2.x + a.y * wl2.y + xv.x * wr2.x + xv.y * wr2.y;
            }
        }
    }

    float b0 = b[j0], b1 = b[j0 + 32], b2 = b[j0 + 64];
    #pragma unroll
    for (int i = 0; i < 4; ++i) {
        int node = base + ng + i * 8;
        if (node < N) {
            h[node * 96 + j0     ] = fmaxf(acc[i][0] + b0, 0.f);
            h[node * 96 + j0 + 32] = fmaxf(acc[i][1] + b1, 0.f);
            h[node * 96 + j0 + 64] = fmaxf(acc[i][2] + b2, 0.f);
        }
    }
}

// ---------------------------------------------------------------------------
// Layer-2 projection (before aggregation; linearity of mean):
//   pl = h @ W2l^T   pr = h @ W2r^T    (both [N x 40])
// Wcat (80x96) staged fully in LDS (stride 98). 32 nodes/block.
// ---------------------------------------------------------------------------
__global__ __launch_bounds__(256) void proj2_kernel(const float* __restrict__ h,
                                                    const float* __restrict__ Wl,
                                                    const float* __restrict__ Wr,
                                                    float* __restrict__ pl,
                                                    float* __restrict__ pr, int N) {
    __shared__ float sW[80 * 98];
    __shared__ float sH[32 * 96];
    int tid  = threadIdx.x;
    int base = blockIdx.x * 32;

    // Stage sW: 80 rows x 48 float2 = 3840 f2, 15/thread.
    for (int t = 0; t < 15; ++t) {
        int flat = tid + t * 256;
        int j  = flat / 48;
        int kh = flat - j * 48;
        float2 w = (j < 40) ? ((const float2*)Wl)[j * 48 + kh]
                            : ((const float2*)Wr)[(j - 40) * 48 + kh];
        *(float2*)&sW[j * 98 + 2 * kh] = w;
    }
    // Stage sH: 768 f4, 3/thread.
    for (int t = 0; t < 3; ++t) {
        int flat = tid + t * 256;
        int n = flat / 24;
        int q = flat - 24 * n;
        int node = base + n;
        float4 v = {0.f, 0.f, 0.f, 0.f};
        if (node < N) v = ((const float4*)h)[node * 24 + q];
        *(float4*)&sH[n * 96 + 4 * q] = v;
    }
    __syncthreads();

    int j0 = tid & 31;
    int ng = tid >> 5;
    bool has2 = (j0 < 16);
    float acc[4][3] = {};
    #pragma unroll 8
    for (int ks = 0; ks < 48; ++ks) {
        float2 w0 = *(const float2*)&sW[ j0       * 98 + 2 * ks];
        float2 w1 = *(const float2*)&sW[(j0 + 32) * 98 + 2 * ks];
        float2 w2 = {0.f, 0.f};
        if (has2) w2 = *(const float2*)&sW[(j0 + 64) * 98 + 2 * ks];
        #pragma unroll
        for (int i = 0; i < 4; ++i) {
            float2 hv = *(const float2*)&sH[(ng + i * 8) * 96 + 2 * ks];
            acc[i][0] += hv.x * w0.x + hv.y * w0.y;
            acc[i][1] += hv.x * w1.x + hv.y * w1.y;
            acc[i][2] += hv.x * w2.x + hv.y * w2.y;
        }
    }
    #pragma unroll
    for (int i = 0; i < 4; ++i) {
        int node = base + ng + i * 8;
        if (node < N) {
            pl[node * 40 + j0] = acc[i][0];
            int o1 = j0 + 32;
            if (o1 < 40) pl[node * 40 + o1] = acc[i][1];
            else         pr[node * 40 + o1 - 40] = acc[i][1];
            if (has2)    pr[node * 40 + j0 + 24] = acc[i][2];
        }
    }
}

// ---------------------------------------------------------------------------
// Final: per-node gather-mean of pl (40 floats) + b2 + pr, then log_softmax.
// One wave per node; lane<40 active; shuffle reductions.
// ---------------------------------------------------------------------------
__global__ __launch_bounds__(256) void final_kernel(const float* __restrict__ pl,
                                                    const float* __restrict__ pr,
                                                    const float* __restrict__ b,
                                                    const int* __restrict__ rp,
                                                    const int* __restrict__ col,
                                                    float* __restrict__ out, int N) {
    int w    = threadIdx.x >> 6;
    int lane = threadIdx.x & 63;
    int n = blockIdx.x * 4 + w;
    if (n >= N) return;
    int s = rp[n], e = rp[n + 1];
    bool act = lane < NCLASS;
    float acc = 0.f;
    int i = s;
    for (; i + 1 < e; i += 2) {
        int c0 = col[i], c1 = col[i + 1];
        if (act) acc += pl[c0 * 40 + lane] + pl[c1 * 40 + lane];
    }
    if (i < e) {
        int c = col[i];
        if (act) acc += pl[c * 40 + lane];
    }
    float v = -INFINITY;
    if (act) {
        int deg = e - s;
        float inv = 1.0f / (float)(deg > 1 ? deg : 1);
        v = acc * inv + b[lane] + pr[n * 40 + lane];
    }
    float m = v;
    #pragma unroll
    for (int off = 32; off >= 1; off >>= 1) m = fmaxf(m, __shfl_xor(m, off));
    float ex = act ? __expf(v - m) : 0.f;
    float ssum = ex;
    #pragma unroll
    for (int off = 32; off >= 1; off >>= 1) ssum += __shfl_xor(ssum, off);
    if (act) out[n * 40 + lane] = v - m - __logf(ssum);
}

// ---------------------------------------------------------------------------
// Host launcher
// ---------------------------------------------------------------------------
extern "C" void kernel_launch(void* const* d_in, const int* in_sizes, int n_in,
                              void* d_out, int out_size, void* d_ws, size_t ws_size,
                              hipStream_t stream) {
    const float* x   = (const float*)d_in[0];
    const int*   ei  = (const int*)  d_in[1];
    const float* W1l = (const float*)d_in[2];
    const float* b1  = (const float*)d_in[3];
    const float* W1r = (const float*)d_in[4];
    const float* W2l = (const float*)d_in[5];
    const float* b2  = (const float*)d_in[6];
    const float* W2r = (const float*)d_in[7];
    float* out = (float*)d_out;

    const int N = in_sizes[0] / NFEAT;   // 50000
    const int E = in_sizes[1] / 2;       // 800000
    const int nb   = (N + 1023) / 1024;  // scan blocks (49)
    const int NPAD = nb * 1024;          // 50176

    // Workspace layout (bytes):
    char* ws = (char*)d_ws;
    int*   cnt  = (int*)(ws);                         // NPAD ints
    int*   rp   = (int*)(ws + (size_t)NPAD * 4);      // NPAD ints (row_ptr)
    int*   bsum = (int*)(ws + (size_t)NPAD * 8);      // 64 ints
    int*   fill = (int*)(ws + (size_t)NPAD * 8 + 256);
    int*   col  = (int*)(ws + (size_t)NPAD * 12 + 256);
    char*  fbase = ws + (size_t)NPAD * 12 + 256 + (size_t)E * 4;
    size_t fb = ((size_t)fbase - (size_t)ws + 255) & ~(size_t)255;
    float* agg = (float*)(ws + fb);                   // N*96 floats (reused: pl/pr)
    float* h   = agg + (size_t)N * 96;
    float* pl  = agg;                                 // alias: agg dead after l1
    float* pr  = agg + (size_t)N * 40;

    // CSR build.
    hipMemsetAsync(cnt, 0, (size_t)NPAD * 4, stream);
    hist_kernel <<<(E + 255) / 256, 256, 0, stream>>>(ei, cnt, E);
    scan1_kernel<<<nb, 256, 0, stream>>>(cnt, rp, bsum);
    scan2_kernel<<<1, 64, 0, stream>>>(bsum, nb);
    scan3_kernel<<<nb, 256, 0, stream>>>(rp, bsum, fill);
    fill_kernel <<<(E + 255) / 256, 256, 0, stream>>>(ei, fill, col, E);

    // Layer 1.
    agg1_kernel<<<(N * 24 + 255) / 256, 256, 0, stream>>>(
        (const float4*)x, rp, col, (float4*)agg, N);
    l1_kernel<<<(N + 31) / 32, 256, 0, stream>>>(x, agg, W1l, b1, W1r, h, N);

    // Layer 2: project first (mean commutes with linear), aggregate 40-dim.
    proj2_kernel<<<(N + 31) / 32, 256, 0, stream>>>(h, W2l, W2r, pl, pr, N);
    final_kernel<<<(N + 3) / 4, 256, 0, stream>>>(pl, pr, b2, rp, col, out, N);
}

// Round 4
// 281.758 us; speedup vs baseline: 3.0062x; 1.5255x over previous
//
#include <hip/hip_runtime.h>
#include <math.h>

#define NCLASS 40

typedef __attribute__((ext_vector_type(8))) short short8;   // 8 bf16 = 4 VGPRs
typedef __attribute__((ext_vector_type(4))) float float4v;  // MFMA 16x16 C/D

__device__ __forceinline__ unsigned short f2bf(float f) {
    union { float f; unsigned u; } v; v.f = f;
    unsigned r = v.u + 0x7fffu + ((v.u >> 16) & 1u);   // round-nearest-even
    return (unsigned short)(r >> 16);
}
__device__ __forceinline__ float bf2f(unsigned int s) {
    union { unsigned u; float f; } v; v.u = s << 16; return v.f;
}

// ---------------------------------------------------------------------------
// CSR construction (unchanged from R3): histogram -> scan -> position fill.
// ---------------------------------------------------------------------------
__global__ __launch_bounds__(256) void hist_kernel(const int* __restrict__ ei,
                                                   int* __restrict__ cnt, int E) {
    int e = blockIdx.x * 256 + threadIdx.x;
    if (e < E) atomicAdd(&cnt[ei[E + e]], 1);
}

__global__ __launch_bounds__(256) void scan1_kernel(const int* __restrict__ cnt,
                                                    int* __restrict__ rp,
                                                    int* __restrict__ bsum) {
    __shared__ int sdata[256];
    int tid  = threadIdx.x;
    int base = blockIdx.x * 1024 + tid * 4;
    int v0 = cnt[base], v1 = cnt[base + 1], v2 = cnt[base + 2], v3 = cnt[base + 3];
    int tsum = v0 + v1 + v2 + v3;
    sdata[tid] = tsum;
    __syncthreads();
    int mine = tsum;
    for (int off = 1; off < 256; off <<= 1) {
        int other = (tid >= off) ? sdata[tid - off] : 0;
        __syncthreads();
        mine += other;
        sdata[tid] = mine;
        __syncthreads();
    }
    int excl = mine - tsum;
    rp[base]     = excl;
    rp[base + 1] = excl + v0;
    rp[base + 2] = excl + v0 + v1;
    rp[base + 3] = excl + v0 + v1 + v2;
    if (tid == 255) bsum[blockIdx.x] = mine;
}

__global__ void scan2_kernel(int* __restrict__ bsum, int nb) {
    if (threadIdx.x == 0 && blockIdx.x == 0) {
        int acc = 0;
        for (int i = 0; i < nb; ++i) { int v = bsum[i]; bsum[i] = acc; acc += v; }
    }
}

__global__ __launch_bounds__(256) void scan3_kernel(int* __restrict__ rp,
                                                    const int* __restrict__ bsum,
                                                    int* __restrict__ fill) {
    int base = blockIdx.x * 1024 + threadIdx.x * 4;
    int off  = bsum[blockIdx.x];
    #pragma unroll
    for (int t = 0; t < 4; ++t) {
        int v = rp[base + t] + off;
        rp[base + t]   = v;
        fill[base + t] = v;
    }
}

__global__ __launch_bounds__(256) void fill_kernel(const int* __restrict__ ei,
                                                   int* __restrict__ fill,
                                                   int* __restrict__ col, int E) {
    int e = blockIdx.x * 256 + threadIdx.x;
    if (e < E) {
        int dst = ei[E + e];
        int src = ei[e];
        int pos = atomicAdd(&fill[dst], 1);
        col[pos] = src;
    }
}

// ---------------------------------------------------------------------------
// Convert x (fp32) into the x-half of combined rows axb[node][192] (bf16):
// axb[n][96..191] = bf16(x[n][0..95]). Agg-half written by agg1_kernel.
// ---------------------------------------------------------------------------
__global__ __launch_bounds__(256) void xconv_kernel(const float4* __restrict__ x4,
                                                    unsigned short* __restrict__ axb,
                                                    int N) {
    int idx = blockIdx.x * 256 + threadIdx.x;
    if (idx >= N * 24) return;
    int n = idx / 24, q = idx - n * 24;
    float4 v = x4[idx];
    ushort4 o;
    o.x = f2bf(v.x); o.y = f2bf(v.y); o.z = f2bf(v.z); o.w = f2bf(v.w);
    *(ushort4*)(axb + (size_t)n * 192 + 96 + q * 4) = o;
}

// ---------------------------------------------------------------------------
// Convert W1l|W1r (fp32 [96][96] each) into frag-order bf16 wb1:
// logical Wcat[j][k2] (k2<96 -> W1l, else W1r), laid out so a wave's B-frag
// for (kc, jt) is 64 lanes x 16 B contiguous:
//   slot = kc*6 + jt;  elem((slot,lane,j8)) = Wcat[jt*16+(lane&15)]
//                                               [kc*32+(lane>>4)*8+j8]
// ---------------------------------------------------------------------------
__global__ __launch_bounds__(256) void wconv1_kernel(const float* __restrict__ Wl,
                                                     const float* __restrict__ Wr,
                                                     unsigned short* __restrict__ wb) {
    int t = blockIdx.x * 256 + threadIdx.x;     // 36 slots * 64 lanes = 2304
    if (t >= 36 * 64) return;
    int s = t >> 6, lane = t & 63;
    int kc = s / 6, jt = s - kc * 6;
    int j  = jt * 16 + (lane & 15);
    int k2 = kc * 32 + (lane >> 4) * 8;
    const float* src = (k2 < 96) ? (Wl + j * 96 + k2) : (Wr + j * 96 + (k2 - 96));
    ushort4 o0, o1;
    o0.x = f2bf(src[0]); o0.y = f2bf(src[1]); o0.z = f2bf(src[2]); o0.w = f2bf(src[3]);
    o1.x = f2bf(src[4]); o1.y = f2bf(src[5]); o1.z = f2bf(src[6]); o1.w = f2bf(src[7]);
    *(ushort4*)(wb + t * 8)     = o0;
    *(ushort4*)(wb + t * 8 + 4) = o1;
}

// Same for W2cat (80 rows: j<40 -> W2l, else W2r), K=96 -> 15 slots (kc*5+jt).
__global__ __launch_bounds__(256) void wconv2_kernel(const float* __restrict__ Wl,
                                                     const float* __restrict__ Wr,
                                                     unsigned short* __restrict__ wb) {
    int t = blockIdx.x * 256 + threadIdx.x;     // 15 slots * 64 lanes = 960
    if (t >= 15 * 64) return;
    int s = t >> 6, lane = t & 63;
    int kc = s / 5, jt = s - kc * 5;
    int j  = jt * 16 + (lane & 15);
    int k2 = kc * 32 + (lane >> 4) * 8;
    const float* src = (j < 40) ? (Wl + j * 96 + k2) : (Wr + (j - 40) * 96 + k2);
    ushort4 o0, o1;
    o0.x = f2bf(src[0]); o0.y = f2bf(src[1]); o0.z = f2bf(src[2]); o0.w = f2bf(src[3]);
    o1.x = f2bf(src[4]); o1.y = f2bf(src[5]); o1.z = f2bf(src[6]); o1.w = f2bf(src[7]);
    *(ushort4*)(wb + t * 8)     = o0;
    *(ushort4*)(wb + t * 8 + 4) = o1;
}

// ---------------------------------------------------------------------------
// Layer-1 aggregation: gather-mean of bf16 x rows (axb x-half) via CSR,
// fp32 accumulate, write bf16 into axb agg-half. Thread = (node, 16B chunk).
// ---------------------------------------------------------------------------
__global__ __launch_bounds__(256) void agg1_kernel(const int* __restrict__ rp,
                                                   const int* __restrict__ col,
                                                   unsigned short* __restrict__ axb,
                                                   int N) {
    int idx = blockIdx.x * 256 + threadIdx.x;
    if (idx >= N * 12) return;
    int n = idx / 12, q = idx - n * 12;
    int s = rp[n], e = rp[n + 1];
    float a0=0.f,a1=0.f,a2=0.f,a3=0.f,a4=0.f,a5=0.f,a6=0.f,a7=0.f;
    int i = s;
    for (; i + 1 < e; i += 2) {
        int c0 = col[i], c1 = col[i + 1];
        uint4 u0 = *(const uint4*)(axb + (size_t)c0 * 192 + 96 + q * 8);
        uint4 u1 = *(const uint4*)(axb + (size_t)c1 * 192 + 96 + q * 8);
        a0 += bf2f(u0.x & 0xffffu) + bf2f(u1.x & 0xffffu);
        a1 += bf2f(u0.x >> 16)     + bf2f(u1.x >> 16);
        a2 += bf2f(u0.y & 0xffffu) + bf2f(u1.y & 0xffffu);
        a3 += bf2f(u0.y >> 16)     + bf2f(u1.y >> 16);
        a4 += bf2f(u0.z & 0xffffu) + bf2f(u1.z & 0xffffu);
        a5 += bf2f(u0.z >> 16)     + bf2f(u1.z >> 16);
        a6 += bf2f(u0.w & 0xffffu) + bf2f(u1.w & 0xffffu);
        a7 += bf2f(u0.w >> 16)     + bf2f(u1.w >> 16);
    }
    if (i < e) {
        uint4 u0 = *(const uint4*)(axb + (size_t)col[i] * 192 + 96 + q * 8);
        a0 += bf2f(u0.x & 0xffffu); a1 += bf2f(u0.x >> 16);
        a2 += bf2f(u0.y & 0xffffu); a3 += bf2f(u0.y >> 16);
        a4 += bf2f(u0.z & 0xffffu); a5 += bf2f(u0.z >> 16);
        a6 += bf2f(u0.w & 0xffffu); a7 += bf2f(u0.w >> 16);
    }
    int deg = e - s;
    float inv = 1.0f / (float)(deg > 1 ? deg : 1);
    ushort4 o0, o1;
    o0.x = f2bf(a0 * inv); o0.y = f2bf(a1 * inv);
    o0.z = f2bf(a2 * inv); o0.w = f2bf(a3 * inv);
    o1.x = f2bf(a4 * inv); o1.y = f2bf(a5 * inv);
    o1.z = f2bf(a6 * inv); o1.w = f2bf(a7 * inv);
    *(ushort4*)(axb + (size_t)n * 192 + q * 8)     = o0;
    *(ushort4*)(axb + (size_t)n * 192 + q * 8 + 4) = o1;
}

// ---------------------------------------------------------------------------
// Layer-1 MFMA GEMM: h = relu(axb[N x 192] @ Wcat^T + b1), h bf16 [N x 96].
// 256 thr = 4 waves; wave handles 32 nodes (2 m-tiles of 16); K = 6 chunks
// of 32. Verified gfx950 layouts: A m=lane&15,k=quad*8+j; C/D col=lane&15,
// row=quad*4+reg. B-frags are contiguous 16 B/lane reads from frag-order wb1.
// Pad rows (node >= N) carry garbage but only pollute their own D rows.
// ---------------------------------------------------------------------------
__global__ __launch_bounds__(256) void l1_mfma_kernel(const unsigned short* __restrict__ axb,
                                                      const unsigned short* __restrict__ wb,
                                                      const float* __restrict__ bias,
                                                      unsigned short* __restrict__ h,
                                                      int N) {
    int wave = threadIdx.x >> 6, lane = threadIdx.x & 63;
    int nbase = blockIdx.x * 128 + wave * 32;
    int mrow = lane & 15, quad = lane >> 4;
    float4v acc[2][6] = {};
    const short8* W = (const short8*)wb;

    #pragma unroll
    for (int kc = 0; kc < 6; ++kc) {
        short8 a0 = *(const short8*)(axb + (size_t)(nbase + mrow)      * 192 + kc * 32 + quad * 8);
        short8 a1 = *(const short8*)(axb + (size_t)(nbase + 16 + mrow) * 192 + kc * 32 + quad * 8);
        #pragma unroll
        for (int jt = 0; jt < 6; ++jt) {
            short8 b = W[(kc * 6 + jt) * 64 + lane];
            acc[0][jt] = __builtin_amdgcn_mfma_f32_16x16x32_bf16(a0, b, acc[0][jt], 0, 0, 0);
            acc[1][jt] = __builtin_amdgcn_mfma_f32_16x16x32_bf16(a1, b, acc[1][jt], 0, 0, 0);
        }
    }

    #pragma unroll
    for (int jt = 0; jt < 6; ++jt) {
        int j = jt * 16 + mrow;
        float bj = bias[j];
        #pragma unroll
        for (int mt = 0; mt < 2; ++mt) {
            #pragma unroll
            for (int r = 0; r < 4; ++r) {
                int node = nbase + mt * 16 + quad * 4 + r;
                if (node < N)
                    h[(size_t)node * 96 + j] = f2bf(fmaxf(acc[mt][jt][r] + bj, 0.f));
            }
        }
    }
}

// ---------------------------------------------------------------------------
// Layer-2 projection MFMA: [pl|pr] = h[N x 96] @ W2cat^T  (80 outputs).
// pl (j<40) stored bf16 (gathered per-edge by final), pr fp32 (read once).
// ---------------------------------------------------------------------------
__global__ __launch_bounds__(256) void proj2_mfma_kernel(const unsigned short* __restrict__ h,
                                                         const unsigned short* __restrict__ wb,
                                                         unsigned short* __restrict__ pl,
                                                         float* __restrict__ pr,
                                                         int N) {
    int wave = threadIdx.x >> 6, lane = threadIdx.x & 63;
    int nbase = blockIdx.x * 128 + wave * 32;
    int mrow = lane & 15, quad = lane >> 4;
    float4v acc[2][5] = {};
    const short8* W = (const short8*)wb;

    #pragma unroll
    for (int kc = 0; kc < 3; ++kc) {
        short8 a0 = *(const short8*)(h + (size_t)(nbase + mrow)      * 96 + kc * 32 + quad * 8);
        short8 a1 = *(const short8*)(h + (size_t)(nbase + 16 + mrow) * 96 + kc * 32 + quad * 8);
        #pragma unroll
        for (int jt = 0; jt < 5; ++jt) {
            short8 b = W[(kc * 5 + jt) * 64 + lane];
            acc[0][jt] = __builtin_amdgcn_mfma_f32_16x16x32_bf16(a0, b, acc[0][jt], 0, 0, 0);
            acc[1][jt] = __builtin_amdgcn_mfma_f32_16x16x32_bf16(a1, b, acc[1][jt], 0, 0, 0);
        }
    }

    #pragma unroll
    for (int jt = 0; jt < 5; ++jt) {
        int j = jt * 16 + mrow;
        #pragma unroll
        for (int mt = 0; mt < 2; ++mt) {
            #pragma unroll
            for (int r = 0; r < 4; ++r) {
                int node = nbase + mt * 16 + quad * 4 + r;
                if (node < N) {
                    float v = acc[mt][jt][r];
                    if (j < 40) pl[(size_t)node * 40 + j] = f2bf(v);
                    else        pr[(size_t)node * 40 + (j - 40)] = v;
                }
            }
        }
    }
}

// ---------------------------------------------------------------------------
// Final: logits = mean_{src}(pl[src]) + b2 + pr[n]; log_softmax. One wave
// per node, lanes < 40 active, shuffle reductions.
// ---------------------------------------------------------------------------
__global__ __launch_bounds__(256) void final_kernel(const unsigned short* __restrict__ pl,
                                                    const float* __restrict__ pr,
                                                    const float* __restrict__ b,
                                                    const int* __restrict__ rp,
                                                    const int* __restrict__ col,
                                                    float* __restrict__ out, int N) {
    int w    = threadIdx.x >> 6;
    int lane = threadIdx.x & 63;
    int n = blockIdx.x * 4 + w;
    if (n >= N) return;
    int s = rp[n], e = rp[n + 1];
    bool act = lane < NCLASS;
    float acc = 0.f;
    int i = s;
    for (; i + 1 < e; i += 2) {
        int c0 = col[i], c1 = col[i + 1];
        if (act) acc += bf2f(pl[(size_t)c0 * 40 + lane]) + bf2f(pl[(size_t)c1 * 40 + lane]);
    }
    if (i < e) {
        int c = col[i];
        if (act) acc += bf2f(pl[(size_t)c * 40 + lane]);
    }
    float v = -INFINITY;
    if (act) {
        int deg = e - s;
        float inv = 1.0f / (float)(deg > 1 ? deg : 1);
        v = acc * inv + b[lane] + pr[(size_t)n * 40 + lane];
    }
    float m = v;
    #pragma unroll
    for (int off = 32; off >= 1; off >>= 1) m = fmaxf(m, __shfl_xor(m, off));
    float ex = act ? __expf(v - m) : 0.f;
    float ssum = ex;
    #pragma unroll
    for (int off = 32; off >= 1; off >>= 1) ssum += __shfl_xor(ssum, off);
    if (act) out[(size_t)n * 40 + lane] = v - m - __logf(ssum);
}

// ---------------------------------------------------------------------------
// Host launcher
// ---------------------------------------------------------------------------
extern "C" void kernel_launch(void* const* d_in, const int* in_sizes, int n_in,
                              void* d_out, int out_size, void* d_ws, size_t ws_size,
                              hipStream_t stream) {
    const float* x   = (const float*)d_in[0];
    const int*   ei  = (const int*)  d_in[1];
    const float* W1l = (const float*)d_in[2];
    const float* b1  = (const float*)d_in[3];
    const float* W1r = (const float*)d_in[4];
    const float* W2l = (const float*)d_in[5];
    const float* b2  = (const float*)d_in[6];
    const float* W2r = (const float*)d_in[7];
    float* out = (float*)d_out;

    const int N = in_sizes[0] / 96;      // 50000
    const int E = in_sizes[1] / 2;       // 800000
    const int nb   = (N + 1023) / 1024;  // 49 scan blocks
    const int NPAD = nb * 1024;          // 50176
    const int NB   = (N + 127) / 128;    // 391 MFMA blocks (128 nodes each)
    const int NP2  = NB * 128;           // 50048 padded rows

    // Workspace layout (byte offsets, all 256-aligned):
    char* ws = (char*)d_ws;
    int*            cnt  = (int*)(ws);                           // NPAD i32
    int*            rp   = (int*)(ws + 200704);                  // NPAD i32
    int*            bsum = (int*)(ws + 401408);                  // 64 i32
    int*            fill = (int*)(ws + 401664);                  // NPAD i32
    int*            col  = (int*)(ws + 602368);                  // E i32
    unsigned short* axb  = (unsigned short*)(ws + 3802368);      // NP2 x 192 bf16
    unsigned short* h    = (unsigned short*)(ws + 23020800);     // NP2 x 96 bf16
    unsigned short* wb1  = (unsigned short*)(ws + 32630016);     // 36 KB frag-order
    unsigned short* wb2  = (unsigned short*)(ws + 32666880);     // 15 KB frag-order
    unsigned short* pl   = (unsigned short*)(ws + 32682240);     // NP2 x 40 bf16
    float*          pr   = (float*)(ws + 36686080);              // N x 40 fp32

    // CSR build.
    hipMemsetAsync(cnt, 0, (size_t)NPAD * 4, stream);
    hist_kernel <<<(E + 255) / 256, 256, 0, stream>>>(ei, cnt, E);
    scan1_kernel<<<nb, 256, 0, stream>>>(cnt, rp, bsum);
    scan2_kernel<<<1, 64, 0, stream>>>(bsum, nb);
    scan3_kernel<<<nb, 256, 0, stream>>>(rp, bsum, fill);
    fill_kernel <<<(E + 255) / 256, 256, 0, stream>>>(ei, fill, col, E);

    // bf16 conversions (x and both weight sets).
    xconv_kernel <<<(N * 24 + 255) / 256, 256, 0, stream>>>((const float4*)x, axb, N);
    wconv1_kernel<<<9, 256, 0, stream>>>(W1l, W1r, wb1);
    wconv2_kernel<<<4, 256, 0, stream>>>(W2l, W2r, wb2);

    // Layer 1: gather-mean (bf16) then MFMA GEMM.
    agg1_kernel   <<<(N * 12 + 255) / 256, 256, 0, stream>>>(rp, col, axb, N);
    l1_mfma_kernel<<<NB, 256, 0, stream>>>(axb, wb1, b1, h, N);

    // Layer 2: project first (mean commutes with linear), then aggregate 40-d.
    proj2_mfma_kernel<<<NB, 256, 0, stream>>>(h, wb2, pl, pr, N);
    final_kernel<<<(N + 3) / 4, 256, 0, stream>>>(pl, pr, b2, rp, col, out, N);
}

// Round 5
// 238.032 us; speedup vs baseline: 3.5584x; 1.1837x over previous
//
#include <hip/hip_runtime.h>
#include <math.h>

#define NCLASS 40
#define MAXB   512      // max dst-buckets (node>>7); N=50000 -> 391 used
#define EPB    16384    // edges per block in bhist/bin

typedef __attribute__((ext_vector_type(8))) short short8;   // 8 bf16 = 4 VGPRs
typedef __attribute__((ext_vector_type(4))) float float4v;  // MFMA 16x16 C/D

__device__ __forceinline__ unsigned short f2bf(float f) {
    union { float f; unsigned u; } v; v.f = f;
    unsigned r = v.u + 0x7fffu + ((v.u >> 16) & 1u);   // round-nearest-even
    return (unsigned short)(r >> 16);
}
__device__ __forceinline__ float bf2f(unsigned int s) {
    union { unsigned u; float f; } v; v.u = s << 16; return v.f;
}

// ---------------------------------------------------------------------------
// CSR build, phase 0: coarse histogram over dst>>7 buckets (LDS-staged).
// ---------------------------------------------------------------------------
__global__ __launch_bounds__(256) void bhist_kernel(const int* __restrict__ ei,
                                                    int* __restrict__ gbh,
                                                    int E, int nbucket) {
    __shared__ int hcnt[MAXB];
    int tid = threadIdx.x;
    for (int t = tid; t < nbucket; t += 256) hcnt[t] = 0;
    __syncthreads();
    int e0 = blockIdx.x * EPB;
    for (int it = 0; it < EPB / 256; ++it) {
        int e = e0 + it * 256 + tid;
        if (e < E) atomicAdd(&hcnt[ei[E + e] >> 7], 1);
    }
    __syncthreads();
    for (int t = tid; t < nbucket; t += 256) {
        int c = hcnt[t];
        if (c > 0) atomicAdd(&gbh[t], c);
    }
}

// ---------------------------------------------------------------------------
// Phase 1: exclusive scan of bucket counts (single block), init fill cursors,
// write rp sentinel.
// ---------------------------------------------------------------------------
__global__ __launch_bounds__(512) void bscan_kernel(const int* __restrict__ gbh,
                                                    int* __restrict__ gbase,
                                                    int* __restrict__ fillpos,
                                                    int* __restrict__ rp,
                                                    int N, int E, int nbucket) {
    __shared__ int s[512];
    int tid = threadIdx.x;
    int v = (tid < nbucket) ? gbh[tid] : 0;
    s[tid] = v;
    __syncthreads();
    for (int off = 1; off < 512; off <<= 1) {
        int o = (tid >= off) ? s[tid - off] : 0;
        __syncthreads();
        s[tid] += o;
        __syncthreads();
    }
    if (tid < nbucket) { gbase[tid] = s[tid] - v; fillpos[tid] = 0; }
    if (tid == nbucket) gbase[nbucket] = E;
    if (tid == 0) rp[N] = E;
}

// ---------------------------------------------------------------------------
// Phase 2: bin edges into bucket regions as (src,dst) pairs. Two LDS passes:
// count, reserve one contiguous run per (block,bucket) via a single global
// atomic, then scatter. Writes are block-private contiguous runs.
// ---------------------------------------------------------------------------
__global__ __launch_bounds__(256) void bin_kernel(const int* __restrict__ ei,
                                                  const int* __restrict__ gbase,
                                                  int* __restrict__ fillpos,
                                                  uint2* __restrict__ tmp,
                                                  int E, int nbucket) {
    __shared__ int hcnt[MAXB];
    __shared__ int lbase[MAXB];
    int tid = threadIdx.x;
    int e0  = blockIdx.x * EPB;
    for (int t = tid; t < nbucket; t += 256) hcnt[t] = 0;
    __syncthreads();
    for (int it = 0; it < EPB / 256; ++it) {
        int e = e0 + it * 256 + tid;
        if (e < E) atomicAdd(&hcnt[ei[E + e] >> 7], 1);
    }
    __syncthreads();
    for (int t = tid; t < nbucket; t += 256) {
        int c = hcnt[t];
        int base = (c > 0) ? atomicAdd(&fillpos[t], c) : 0;
        lbase[t] = gbase[t] + base;
        hcnt[t]  = 0;
    }
    __syncthreads();
    for (int it = 0; it < EPB / 256; ++it) {
        int e = e0 + it * 256 + tid;
        if (e < E) {
            int src = ei[e], dst = ei[E + e];
            int b   = dst >> 7;
            int ofs = atomicAdd(&hcnt[b], 1);
            tmp[lbase[b] + ofs] = make_uint2((unsigned)src, (unsigned)dst);
        }
    }
}

// ---------------------------------------------------------------------------
// Phase 3: one block per bucket -> exact CSR (rp + col). LDS per-node count,
// scan over the 128 local nodes, then position fill. col writes are
// bucket-contiguous (~8 KB sequential region).
// ---------------------------------------------------------------------------
__global__ __launch_bounds__(256) void bucket_csr_kernel(const uint2* __restrict__ tmp,
                                                         const int* __restrict__ gbase,
                                                         int* __restrict__ rp,
                                                         int* __restrict__ col, int N) {
    __shared__ int ncnt[128], nofs[128], sscan[128];
    int b   = blockIdx.x;
    int tid = threadIdx.x;
    int s0 = gbase[b], s1 = gbase[b + 1];
    if (tid < 128) ncnt[tid] = 0;
    __syncthreads();
    for (int i = s0 + tid; i < s1; i += 256)
        atomicAdd(&ncnt[(int)tmp[i].y - (b << 7)], 1);
    __syncthreads();
    int v = (tid < 128) ? ncnt[tid] : 0;
    if (tid < 128) sscan[tid] = v;
    __syncthreads();
    for (int off = 1; off < 128; off <<= 1) {
        int o = (tid < 128 && tid >= off) ? sscan[tid - off] : 0;
        __syncthreads();
        if (tid < 128) sscan[tid] += o;
        __syncthreads();
    }
    if (tid < 128) {
        nofs[tid] = sscan[tid] - v;       // exclusive prefix
        int node = (b << 7) + tid;
        if (node < N) rp[node] = s0 + nofs[tid];
        ncnt[tid] = 0;
    }
    __syncthreads();
    for (int i = s0 + tid; i < s1; i += 256) {
        uint2 t2 = tmp[i];
        int d   = (int)t2.y - (b << 7);
        int ofs = atomicAdd(&ncnt[d], 1);
        col[s0 + nofs[d] + ofs] = (int)t2.x;
    }
}

// ---------------------------------------------------------------------------
// Convert x (fp32) into the x-half of combined rows axb[node][192] (bf16).
// ---------------------------------------------------------------------------
__global__ __launch_bounds__(256) void xconv_kernel(const float4* __restrict__ x4,
                                                    unsigned short* __restrict__ axb,
                                                    int N) {
    int idx = blockIdx.x * 256 + threadIdx.x;
    if (idx >= N * 24) return;
    int n = idx / 24, q = idx - n * 24;
    float4 v = x4[idx];
    ushort4 o;
    o.x = f2bf(v.x); o.y = f2bf(v.y); o.z = f2bf(v.z); o.w = f2bf(v.w);
    *(ushort4*)(axb + (size_t)n * 192 + 96 + q * 4) = o;
}

// ---------------------------------------------------------------------------
// Frag-order bf16 weight conversion (layer 1: Wcat = [W1l | W1r], 96 rows,
// K=192): slot = kc*6 + jt; elem(slot,lane,j8) = Wcat[jt*16+(lane&15)]
// [kc*32+(lane>>4)*8+j8].
// ---------------------------------------------------------------------------
__global__ __launch_bounds__(256) void wconv1_kernel(const float* __restrict__ Wl,
                                                     const float* __restrict__ Wr,
                                                     unsigned short* __restrict__ wb) {
    int t = blockIdx.x * 256 + threadIdx.x;     // 36 slots * 64 lanes = 2304
    if (t >= 36 * 64) return;
    int s = t >> 6, lane = t & 63;
    int kc = s / 6, jt = s - kc * 6;
    int j  = jt * 16 + (lane & 15);
    int k2 = kc * 32 + (lane >> 4) * 8;
    const float* src = (k2 < 96) ? (Wl + j * 96 + k2) : (Wr + j * 96 + (k2 - 96));
    ushort4 o0, o1;
    o0.x = f2bf(src[0]); o0.y = f2bf(src[1]); o0.z = f2bf(src[2]); o0.w = f2bf(src[3]);
    o1.x = f2bf(src[4]); o1.y = f2bf(src[5]); o1.z = f2bf(src[6]); o1.w = f2bf(src[7]);
    *(ushort4*)(wb + t * 8)     = o0;
    *(ushort4*)(wb + t * 8 + 4) = o1;
}

// Layer 2: W2cat (80 rows: j<40 -> W2l, else W2r), K=96 -> 15 slots (kc*5+jt).
__global__ __launch_bounds__(256) void wconv2_kernel(const float* __restrict__ Wl,
                                                     const float* __restrict__ Wr,
                                                     unsigned short* __restrict__ wb) {
    int t = blockIdx.x * 256 + threadIdx.x;     // 15 slots * 64 lanes = 960
    if (t >= 15 * 64) return;
    int s = t >> 6, lane = t & 63;
    int kc = s / 5, jt = s - kc * 5;
    int j  = jt * 16 + (lane & 15);
    int k2 = kc * 32 + (lane >> 4) * 8;
    const float* src = (j < 40) ? (Wl + j * 96 + k2) : (Wr + (j - 40) * 96 + k2);
    ushort4 o0, o1;
    o0.x = f2bf(src[0]); o0.y = f2bf(src[1]); o0.z = f2bf(src[2]); o0.w = f2bf(src[3]);
    o1.x = f2bf(src[4]); o1.y = f2bf(src[5]); o1.z = f2bf(src[6]); o1.w = f2bf(src[7]);
    *(ushort4*)(wb + t * 8)     = o0;
    *(ushort4*)(wb + t * 8 + 4) = o1;
}

// ---------------------------------------------------------------------------
// Layer-1 aggregation: gather-mean of bf16 x rows via CSR, fp32 accumulate,
// bf16 store into the agg-half of axb. Thread = (node, 16B chunk); 4-edge
// unroll for memory-level parallelism.
// ---------------------------------------------------------------------------
__global__ __launch_bounds__(256) void agg1_kernel(const int* __restrict__ rp,
                                                   const int* __restrict__ col,
                                                   unsigned short* __restrict__ axb,
                                                   int N) {
    int idx = blockIdx.x * 256 + threadIdx.x;
    if (idx >= N * 12) return;
    int n = idx / 12, q = idx - n * 12;
    int s = rp[n], e = rp[n + 1];
    float a0=0.f,a1=0.f,a2=0.f,a3=0.f,a4=0.f,a5=0.f,a6=0.f,a7=0.f;
    int i = s;
    for (; i + 3 < e; i += 4) {
        int c0 = col[i], c1 = col[i+1], c2 = col[i+2], c3 = col[i+3];
        uint4 u0 = *(const uint4*)(axb + (size_t)c0 * 192 + 96 + q * 8);
        uint4 u1 = *(const uint4*)(axb + (size_t)c1 * 192 + 96 + q * 8);
        uint4 u2 = *(const uint4*)(axb + (size_t)c2 * 192 + 96 + q * 8);
        uint4 u3 = *(const uint4*)(axb + (size_t)c3 * 192 + 96 + q * 8);
        a0 += bf2f(u0.x & 0xffffu) + bf2f(u1.x & 0xffffu) + bf2f(u2.x & 0xffffu) + bf2f(u3.x & 0xffffu);
        a1 += bf2f(u0.x >> 16)     + bf2f(u1.x >> 16)     + bf2f(u2.x >> 16)     + bf2f(u3.x >> 16);
        a2 += bf2f(u0.y & 0xffffu) + bf2f(u1.y & 0xffffu) + bf2f(u2.y & 0xffffu) + bf2f(u3.y & 0xffffu);
        a3 += bf2f(u0.y >> 16)     + bf2f(u1.y >> 16)     + bf2f(u2.y >> 16)     + bf2f(u3.y >> 16);
        a4 += bf2f(u0.z & 0xffffu) + bf2f(u1.z & 0xffffu) + bf2f(u2.z & 0xffffu) + bf2f(u3.z & 0xffffu);
        a5 += bf2f(u0.z >> 16)     + bf2f(u1.z >> 16)     + bf2f(u2.z >> 16)     + bf2f(u3.z >> 16);
        a6 += bf2f(u0.w & 0xffffu) + bf2f(u1.w & 0xffffu) + bf2f(u2.w & 0xffffu) + bf2f(u3.w & 0xffffu);
        a7 += bf2f(u0.w >> 16)     + bf2f(u1.w >> 16)     + bf2f(u2.w >> 16)     + bf2f(u3.w >> 16);
    }
    for (; i < e; ++i) {
        uint4 u0 = *(const uint4*)(axb + (size_t)col[i] * 192 + 96 + q * 8);
        a0 += bf2f(u0.x & 0xffffu); a1 += bf2f(u0.x >> 16);
        a2 += bf2f(u0.y & 0xffffu); a3 += bf2f(u0.y >> 16);
        a4 += bf2f(u0.z & 0xffffu); a5 += bf2f(u0.z >> 16);
        a6 += bf2f(u0.w & 0xffffu); a7 += bf2f(u0.w >> 16);
    }
    int deg = e - s;
    float inv = 1.0f / (float)(deg > 1 ? deg : 1);
    ushort4 o0, o1;
    o0.x = f2bf(a0 * inv); o0.y = f2bf(a1 * inv);
    o0.z = f2bf(a2 * inv); o0.w = f2bf(a3 * inv);
    o1.x = f2bf(a4 * inv); o1.y = f2bf(a5 * inv);
    o1.z = f2bf(a6 * inv); o1.w = f2bf(a7 * inv);
    *(ushort4*)(axb + (size_t)n * 192 + q * 8)     = o0;
    *(ushort4*)(axb + (size_t)n * 192 + q * 8 + 4) = o1;
}

// ---------------------------------------------------------------------------
// Layer-1 MFMA GEMM: h = relu(axb[N x 192] @ Wcat^T + b1), h bf16 [N x 96].
// ---------------------------------------------------------------------------
__global__ __launch_bounds__(256) void l1_mfma_kernel(const unsigned short* __restrict__ axb,
                                                      const unsigned short* __restrict__ wb,
                                                      const float* __restrict__ bias,
                                                      unsigned short* __restrict__ h,
                                                      int N) {
    int wave = threadIdx.x >> 6, lane = threadIdx.x & 63;
    int nbase = blockIdx.x * 128 + wave * 32;
    int mrow = lane & 15, quad = lane >> 4;
    float4v acc[2][6] = {};
    const short8* W = (const short8*)wb;

    #pragma unroll
    for (int kc = 0; kc < 6; ++kc) {
        short8 a0 = *(const short8*)(axb + (size_t)(nbase + mrow)      * 192 + kc * 32 + quad * 8);
        short8 a1 = *(const short8*)(axb + (size_t)(nbase + 16 + mrow) * 192 + kc * 32 + quad * 8);
        #pragma unroll
        for (int jt = 0; jt < 6; ++jt) {
            short8 b = W[(kc * 6 + jt) * 64 + lane];
            acc[0][jt] = __builtin_amdgcn_mfma_f32_16x16x32_bf16(a0, b, acc[0][jt], 0, 0, 0);
            acc[1][jt] = __builtin_amdgcn_mfma_f32_16x16x32_bf16(a1, b, acc[1][jt], 0, 0, 0);
        }
    }

    #pragma unroll
    for (int jt = 0; jt < 6; ++jt) {
        int j = jt * 16 + mrow;
        float bj = bias[j];
        #pragma unroll
        for (int mt = 0; mt < 2; ++mt) {
            #pragma unroll
            for (int r = 0; r < 4; ++r) {
                int node = nbase + mt * 16 + quad * 4 + r;
                if (node < N)
                    h[(size_t)node * 96 + j] = f2bf(fmaxf(acc[mt][jt][r] + bj, 0.f));
            }
        }
    }
}

// ---------------------------------------------------------------------------
// Layer-2 projection MFMA: [pl|pr] = h[N x 96] @ W2cat^T (80 outputs).
// pl bf16 with row stride 64 (one 128B line per row); pr fp32.
// ---------------------------------------------------------------------------
__global__ __launch_bounds__(256) void proj2_mfma_kernel(const unsigned short* __restrict__ h,
                                                         const unsigned short* __restrict__ wb,
                                                         unsigned short* __restrict__ pl,
                                                         float* __restrict__ pr,
                                                         int N) {
    int wave = threadIdx.x >> 6, lane = threadIdx.x & 63;
    int nbase = blockIdx.x * 128 + wave * 32;
    int mrow = lane & 15, quad = lane >> 4;
    float4v acc[2][5] = {};
    const short8* W = (const short8*)wb;

    #pragma unroll
    for (int kc = 0; kc < 3; ++kc) {
        short8 a0 = *(const short8*)(h + (size_t)(nbase + mrow)      * 96 + kc * 32 + quad * 8);
        short8 a1 = *(const short8*)(h + (size_t)(nbase + 16 + mrow) * 96 + kc * 32 + quad * 8);
        #pragma unroll
        for (int jt = 0; jt < 5; ++jt) {
            short8 b = W[(kc * 5 + jt) * 64 + lane];
            acc[0][jt] = __builtin_amdgcn_mfma_f32_16x16x32_bf16(a0, b, acc[0][jt], 0, 0, 0);
            acc[1][jt] = __builtin_amdgcn_mfma_f32_16x16x32_bf16(a1, b, acc[1][jt], 0, 0, 0);
        }
    }

    #pragma unroll
    for (int jt = 0; jt < 5; ++jt) {
        int j = jt * 16 + mrow;
        #pragma unroll
        for (int mt = 0; mt < 2; ++mt) {
            #pragma unroll
            for (int r = 0; r < 4; ++r) {
                int node = nbase + mt * 16 + quad * 4 + r;
                if (node < N) {
                    float v = acc[mt][jt][r];
                    if (j < 40) pl[(size_t)node * 64 + j] = f2bf(v);
                    else        pr[(size_t)node * 40 + (j - 40)] = v;
                }
            }
        }
    }
}

// ---------------------------------------------------------------------------
// Final: logits = mean_{src}(pl[src]) + b2 + pr[n]; log_softmax. One wave
// per node, lanes < 40 active, 4-edge unroll, shuffle reductions.
// ---------------------------------------------------------------------------
__global__ __launch_bounds__(256) void final_kernel(const unsigned short* __restrict__ pl,
                                                    const float* __restrict__ pr,
                                                    const float* __restrict__ b,
                                                    const int* __restrict__ rp,
                                                    const int* __restrict__ col,
                                                    float* __restrict__ out, int N) {
    int w    = threadIdx.x >> 6;
    int lane = threadIdx.x & 63;
    int n = blockIdx.x * 4 + w;
    if (n >= N) return;
    int s = rp[n], e = rp[n + 1];
    bool act = lane < NCLASS;
    float acc = 0.f;
    int i = s;
    for (; i + 3 < e; i += 4) {
        int c0 = col[i], c1 = col[i+1], c2 = col[i+2], c3 = col[i+3];
        if (act) acc += bf2f(pl[(size_t)c0 * 64 + lane]) + bf2f(pl[(size_t)c1 * 64 + lane])
                      + bf2f(pl[(size_t)c2 * 64 + lane]) + bf2f(pl[(size_t)c3 * 64 + lane]);
    }
    for (; i < e; ++i) {
        int c = col[i];
        if (act) acc += bf2f(pl[(size_t)c * 64 + lane]);
    }
    float v = -INFINITY;
    if (act) {
        int deg = e - s;
        float inv = 1.0f / (float)(deg > 1 ? deg : 1);
        v = acc * inv + b[lane] + pr[(size_t)n * 40 + lane];
    }
    float m = v;
    #pragma unroll
    for (int off = 32; off >= 1; off >>= 1) m = fmaxf(m, __shfl_xor(m, off));
    float ex = act ? __expf(v - m) : 0.f;
    float ssum = ex;
    #pragma unroll
    for (int off = 32; off >= 1; off >>= 1) ssum += __shfl_xor(ssum, off);
    if (act) out[(size_t)n * 40 + lane] = v - m - __logf(ssum);
}

// ---------------------------------------------------------------------------
// Host launcher
// ---------------------------------------------------------------------------
extern "C" void kernel_launch(void* const* d_in, const int* in_sizes, int n_in,
                              void* d_out, int out_size, void* d_ws, size_t ws_size,
                              hipStream_t stream) {
    const float* x   = (const float*)d_in[0];
    const int*   ei  = (const int*)  d_in[1];
    const float* W1l = (const float*)d_in[2];
    const float* b1  = (const float*)d_in[3];
    const float* W1r = (const float*)d_in[4];
    const float* W2l = (const float*)d_in[5];
    const float* b2  = (const float*)d_in[6];
    const float* W2r = (const float*)d_in[7];
    float* out = (float*)d_out;

    const int N = in_sizes[0] / 96;      // 50000
    const int E = in_sizes[1] / 2;       // 800000
    const int nbucket = (N + 127) >> 7;  // 391
    const int NB   = (N + 127) / 128;    // MFMA blocks (128 nodes each)
    const int NP2  = NB * 128;           // padded rows
    const int nbin = (E + EPB - 1) / EPB;

    // Workspace layout (all offsets 256-aligned).
    auto al = [](size_t v) { return (v + 255) & ~(size_t)255; };
    char* ws = (char*)d_ws;
    size_t o = 0;
    int* gbh     = (int*)(ws + o); o = al(o + (size_t)MAXB * 4);
    int* gbase   = (int*)(ws + o); o = al(o + (size_t)(MAXB + 1) * 4);
    int* fillpos = (int*)(ws + o); o = al(o + (size_t)MAXB * 4);
    int* rp      = (int*)(ws + o); o = al(o + (size_t)(N + 1) * 4);
    uint2* tmp   = (uint2*)(ws + o); o = al(o + (size_t)E * 8);
    int* col     = (int*)(ws + o); o = al(o + (size_t)E * 4);
    size_t off_axb = o;
    unsigned short* axb = (unsigned short*)(ws + o); o = al(o + (size_t)NP2 * 192 * 2);
    unsigned short* h   = (unsigned short*)(ws + o); o = al(o + (size_t)NP2 * 96 * 2);
    unsigned short* wb1 = (unsigned short*)(ws + o); o = al(o + 36 * 64 * 8 * 2);
    unsigned short* wb2 = (unsigned short*)(ws + o); o = al(o + 15 * 64 * 8 * 2);
    unsigned short* pl  = (unsigned short*)(ws + o); o = al(o + (size_t)NP2 * 64 * 2);
    // pr overlays axb (axb is dead after l1_mfma; proj2 runs later). 8MB <= 19.2MB.
    float* pr = (float*)(ws + off_axb);

    // CSR build (bucketed 2-phase sort; no fp atomics, line-friendly writes).
    hipMemsetAsync(gbh, 0, (size_t)MAXB * 4, stream);
    bhist_kernel<<<nbin, 256, 0, stream>>>(ei, gbh, E, nbucket);
    bscan_kernel<<<1, 512, 0, stream>>>(gbh, gbase, fillpos, rp, N, E, nbucket);
    bin_kernel<<<nbin, 256, 0, stream>>>(ei, gbase, fillpos, tmp, E, nbucket);
    bucket_csr_kernel<<<nbucket, 256, 0, stream>>>(tmp, gbase, rp, col, N);

    // bf16 conversions.
    xconv_kernel <<<(N * 24 + 255) / 256, 256, 0, stream>>>((const float4*)x, axb, N);
    wconv1_kernel<<<9, 256, 0, stream>>>(W1l, W1r, wb1);
    wconv2_kernel<<<4, 256, 0, stream>>>(W2l, W2r, wb2);

    // Layer 1: gather-mean (bf16) then MFMA GEMM.
    agg1_kernel   <<<(N * 12 + 255) / 256, 256, 0, stream>>>(rp, col, axb, N);
    l1_mfma_kernel<<<NB, 256, 0, stream>>>(axb, wb1, b1, h, N);

    // Layer 2: project first (mean commutes with linear), aggregate 40-dim.
    proj2_mfma_kernel<<<NB, 256, 0, stream>>>(h, wb2, pl, pr, N);
    final_kernel<<<(N + 3) / 4, 256, 0, stream>>>(pl, pr, b2, rp, col, out, N);
}

// Round 6
// 203.578 us; speedup vs baseline: 4.1606x; 1.1692x over previous
//
#include <hip/hip_runtime.h>
#include <math.h>

#define NCLASS 40
#define MAXB   512      // max dst-buckets (node>>7); N=50000 -> 391 used
#define EPB    4096     // edges per block in bhist/bin (E<=1M -> nbin<=256)

typedef __attribute__((ext_vector_type(8))) short short8;   // 8 bf16 = 4 VGPRs
typedef __attribute__((ext_vector_type(4))) float float4v;  // MFMA 16x16 C/D

__device__ __forceinline__ unsigned short f2bf(float f) {
    union { float f; unsigned u; } v; v.f = f;
    unsigned r = v.u + 0x7fffu + ((v.u >> 16) & 1u);   // round-nearest-even
    return (unsigned short)(r >> 16);
}
__device__ __forceinline__ float bf2f(unsigned int s) {
    union { unsigned u; float f; } v; v.u = s << 16; return v.f;
}

// ---------------------------------------------------------------------------
// CSR build, phase 0: per-block bucket histogram -> histT[bucket][block].
// No global atomics.
// ---------------------------------------------------------------------------
__global__ __launch_bounds__(256) void bhist_kernel(const int* __restrict__ ei,
                                                    int* __restrict__ histT,
                                                    int E, int nbucket, int nbin) {
    __shared__ int hcnt[MAXB];
    int tid = threadIdx.x;
    for (int t = tid; t < nbucket; t += 256) hcnt[t] = 0;
    __syncthreads();
    int e0 = blockIdx.x * EPB;
    for (int it = 0; it < EPB / 256; ++it) {
        int e = e0 + it * 256 + tid;
        if (e < E) atomicAdd(&hcnt[ei[E + e] >> 7], 1);
    }
    __syncthreads();
    for (int t = tid; t < nbucket; t += 256)
        histT[t * nbin + blockIdx.x] = hcnt[t];
}

// ---------------------------------------------------------------------------
// Phase 1a: one block per bucket. Scan the per-block counts (exclusive,
// in place) and emit the bucket total. Requires nbin <= 256.
// ---------------------------------------------------------------------------
__global__ __launch_bounds__(256) void bsum_kernel(int* __restrict__ histT,
                                                   int* __restrict__ gbh, int nbin) {
    __shared__ int s[256];
    int k = blockIdx.x, tid = threadIdx.x;
    int v = (tid < nbin) ? histT[k * nbin + tid] : 0;
    s[tid] = v;
    __syncthreads();
    for (int off = 1; off < 256; off <<= 1) {
        int o = (tid >= off) ? s[tid - off] : 0;
        __syncthreads();
        s[tid] += o;
        __syncthreads();
    }
    if (tid < nbin) histT[k * nbin + tid] = s[tid] - v;   // exclusive prefix
    if (tid == 255) gbh[k] = s[255];                      // bucket total
}

// ---------------------------------------------------------------------------
// Phase 1b: exclusive scan of bucket totals -> gbase; rp sentinel.
// ---------------------------------------------------------------------------
__global__ __launch_bounds__(512) void bscan_kernel(const int* __restrict__ gbh,
                                                    int* __restrict__ gbase,
                                                    int* __restrict__ rp,
                                                    int N, int E, int nbucket) {
    __shared__ int s[512];
    int tid = threadIdx.x;
    int v = (tid < nbucket) ? gbh[tid] : 0;
    s[tid] = v;
    __syncthreads();
    for (int off = 1; off < 512; off <<= 1) {
        int o = (tid >= off) ? s[tid - off] : 0;
        __syncthreads();
        s[tid] += o;
        __syncthreads();
    }
    if (tid < nbucket) gbase[tid] = s[tid] - v;
    if (tid == nbucket) gbase[nbucket] = E;
    if (tid == 0) rp[N] = E;
}

// ---------------------------------------------------------------------------
// Phase 2: single-pass bin. Deterministic per-(block,bucket) base =
// gbase[b] + histT[b][blk]; LDS cursor for within-block offsets. Edges are
// packed 4B: src (16b, requires N<65536) | local-dst (7b) << 16.
// ---------------------------------------------------------------------------
__global__ __launch_bounds__(256) void bin_kernel(const int* __restrict__ ei,
                                                  const int* __restrict__ gbase,
                                                  const int* __restrict__ histT,
                                                  unsigned int* __restrict__ tmp,
                                                  int E, int nbucket, int nbin) {
    __shared__ int lcnt[MAXB];
    __shared__ int lbase[MAXB];
    int tid = threadIdx.x;
    for (int t = tid; t < nbucket; t += 256) {
        lbase[t] = gbase[t] + histT[t * nbin + blockIdx.x];
        lcnt[t]  = 0;
    }
    __syncthreads();
    int e0 = blockIdx.x * EPB;
    for (int it = 0; it < EPB / 256; ++it) {
        int e = e0 + it * 256 + tid;
        if (e < E) {
            int src = ei[e], dst = ei[E + e];
            int b   = dst >> 7;
            int ofs = atomicAdd(&lcnt[b], 1);
            tmp[lbase[b] + ofs] = (unsigned)src | ((unsigned)(dst & 127) << 16);
        }
    }
}

// ---------------------------------------------------------------------------
// Phase 3: one block per bucket -> exact CSR (rp + u16 col). LDS per-node
// count, 128-node scan, position fill. col writes bucket-contiguous.
// ---------------------------------------------------------------------------
__global__ __launch_bounds__(256) void bucket_csr_kernel(const unsigned int* __restrict__ tmp,
                                                         const int* __restrict__ gbase,
                                                         int* __restrict__ rp,
                                                         unsigned short* __restrict__ col,
                                                         int N) {
    __shared__ int ncnt[128], nofs[128], sscan[128];
    int b   = blockIdx.x;
    int tid = threadIdx.x;
    int s0 = gbase[b], s1 = gbase[b + 1];
    if (tid < 128) ncnt[tid] = 0;
    __syncthreads();
    for (int i = s0 + tid; i < s1; i += 256)
        atomicAdd(&ncnt[tmp[i] >> 16], 1);
    __syncthreads();
    int v = (tid < 128) ? ncnt[tid] : 0;
    if (tid < 128) sscan[tid] = v;
    __syncthreads();
    for (int off = 1; off < 128; off <<= 1) {
        int o = (tid < 128 && tid >= off) ? sscan[tid - off] : 0;
        __syncthreads();
        if (tid < 128) sscan[tid] += o;
        __syncthreads();
    }
    if (tid < 128) {
        nofs[tid] = sscan[tid] - v;       // exclusive prefix
        int node = (b << 7) + tid;
        if (node < N) rp[node] = s0 + nofs[tid];
        ncnt[tid] = 0;
    }
    __syncthreads();
    for (int i = s0 + tid; i < s1; i += 256) {
        unsigned int t2 = tmp[i];
        int d   = t2 >> 16;
        int ofs = atomicAdd(&ncnt[d], 1);
        col[s0 + nofs[d] + ofs] = (unsigned short)(t2 & 0xffffu);
    }
}

// ---------------------------------------------------------------------------
// Convert x (fp32) into the x-half of combined rows axb[node][192] (bf16).
// ---------------------------------------------------------------------------
__global__ __launch_bounds__(256) void xconv_kernel(const float4* __restrict__ x4,
                                                    unsigned short* __restrict__ axb,
                                                    int N) {
    int idx = blockIdx.x * 256 + threadIdx.x;
    if (idx >= N * 24) return;
    int n = idx / 24, q = idx - n * 24;
    float4 v = x4[idx];
    ushort4 o;
    o.x = f2bf(v.x); o.y = f2bf(v.y); o.z = f2bf(v.z); o.w = f2bf(v.w);
    *(ushort4*)(axb + (size_t)n * 192 + 96 + q * 4) = o;
}

// ---------------------------------------------------------------------------
// Frag-order bf16 weight conversion, both layers in one launch.
// L1: Wcat=[W1l|W1r] (96 rows, K=192), 36 slots. slot=kc*6+jt;
//     elem = Wcat[jt*16+(lane&15)][kc*32+(lane>>4)*8+j8].
// L2: W2cat (80 rows: j<40->W2l else W2r, K=96), 15 slots (kc*5+jt).
// ---------------------------------------------------------------------------
__global__ __launch_bounds__(256) void wconv_kernel(const float* __restrict__ W1l,
                                                    const float* __restrict__ W1r,
                                                    const float* __restrict__ W2l,
                                                    const float* __restrict__ W2r,
                                                    unsigned short* __restrict__ wb1,
                                                    unsigned short* __restrict__ wb2) {
    int t = blockIdx.x * 256 + threadIdx.x;
    const float* src;
    unsigned short* dst;
    if (t < 36 * 64) {
        int s = t >> 6, lane = t & 63;
        int kc = s / 6, jt = s - kc * 6;
        int j  = jt * 16 + (lane & 15);
        int k2 = kc * 32 + (lane >> 4) * 8;
        src = (k2 < 96) ? (W1l + j * 96 + k2) : (W1r + j * 96 + (k2 - 96));
        dst = wb1 + t * 8;
    } else if (t < 36 * 64 + 15 * 64) {
        int t2 = t - 36 * 64;
        int s = t2 >> 6, lane = t2 & 63;
        int kc = s / 5, jt = s - kc * 5;
        int j  = jt * 16 + (lane & 15);
        int k2 = kc * 32 + (lane >> 4) * 8;
        src = (j < 40) ? (W2l + j * 96 + k2) : (W2r + (j - 40) * 96 + k2);
        dst = wb2 + t2 * 8;
    } else return;
    ushort4 o0, o1;
    o0.x = f2bf(src[0]); o0.y = f2bf(src[1]); o0.z = f2bf(src[2]); o0.w = f2bf(src[3]);
    o1.x = f2bf(src[4]); o1.y = f2bf(src[5]); o1.z = f2bf(src[6]); o1.w = f2bf(src[7]);
    *(ushort4*)(dst)     = o0;
    *(ushort4*)(dst + 4) = o1;
}

// ---------------------------------------------------------------------------
// Layer-1 aggregation: gather-mean of bf16 x rows via CSR, fp32 accumulate,
// bf16 store into the agg-half of axb. Thread = (node, 16B chunk); 4-edge
// unroll for memory-level parallelism.
// ---------------------------------------------------------------------------
__global__ __launch_bounds__(256) void agg1_kernel(const int* __restrict__ rp,
                                                   const unsigned short* __restrict__ col,
                                                   unsigned short* __restrict__ axb,
                                                   int N) {
    int idx = blockIdx.x * 256 + threadIdx.x;
    if (idx >= N * 12) return;
    int n = idx / 12, q = idx - n * 12;
    int s = rp[n], e = rp[n + 1];
    float a0=0.f,a1=0.f,a2=0.f,a3=0.f,a4=0.f,a5=0.f,a6=0.f,a7=0.f;
    int i = s;
    for (; i + 3 < e; i += 4) {
        int c0 = col[i], c1 = col[i+1], c2 = col[i+2], c3 = col[i+3];
        uint4 u0 = *(const uint4*)(axb + (size_t)c0 * 192 + 96 + q * 8);
        uint4 u1 = *(const uint4*)(axb + (size_t)c1 * 192 + 96 + q * 8);
        uint4 u2 = *(const uint4*)(axb + (size_t)c2 * 192 + 96 + q * 8);
        uint4 u3 = *(const uint4*)(axb + (size_t)c3 * 192 + 96 + q * 8);
        a0 += bf2f(u0.x & 0xffffu) + bf2f(u1.x & 0xffffu) + bf2f(u2.x & 0xffffu) + bf2f(u3.x & 0xffffu);
        a1 += bf2f(u0.x >> 16)     + bf2f(u1.x >> 16)     + bf2f(u2.x >> 16)     + bf2f(u3.x >> 16);
        a2 += bf2f(u0.y & 0xffffu) + bf2f(u1.y & 0xffffu) + bf2f(u2.y & 0xffffu) + bf2f(u3.y & 0xffffu);
        a3 += bf2f(u0.y >> 16)     + bf2f(u1.y >> 16)     + bf2f(u2.y >> 16)     + bf2f(u3.y >> 16);
        a4 += bf2f(u0.z & 0xffffu) + bf2f(u1.z & 0xffffu) + bf2f(u2.z & 0xffffu) + bf2f(u3.z & 0xffffu);
        a5 += bf2f(u0.z >> 16)     + bf2f(u1.z >> 16)     + bf2f(u2.z >> 16)     + bf2f(u3.z >> 16);
        a6 += bf2f(u0.w & 0xffffu) + bf2f(u1.w & 0xffffu) + bf2f(u2.w & 0xffffu) + bf2f(u3.w & 0xffffu);
        a7 += bf2f(u0.w >> 16)     + bf2f(u1.w >> 16)     + bf2f(u2.w >> 16)     + bf2f(u3.w >> 16);
    }
    for (; i < e; ++i) {
        uint4 u0 = *(const uint4*)(axb + (size_t)col[i] * 192 + 96 + q * 8);
        a0 += bf2f(u0.x & 0xffffu); a1 += bf2f(u0.x >> 16);
        a2 += bf2f(u0.y & 0xffffu); a3 += bf2f(u0.y >> 16);
        a4 += bf2f(u0.z & 0xffffu); a5 += bf2f(u0.z >> 16);
        a6 += bf2f(u0.w & 0xffffu); a7 += bf2f(u0.w >> 16);
    }
    int deg = e - s;
    float inv = 1.0f / (float)(deg > 1 ? deg : 1);
    ushort4 o0, o1;
    o0.x = f2bf(a0 * inv); o0.y = f2bf(a1 * inv);
    o0.z = f2bf(a2 * inv); o0.w = f2bf(a3 * inv);
    o1.x = f2bf(a4 * inv); o1.y = f2bf(a5 * inv);
    o1.z = f2bf(a6 * inv); o1.w = f2bf(a7 * inv);
    *(ushort4*)(axb + (size_t)n * 192 + q * 8)     = o0;
    *(ushort4*)(axb + (size_t)n * 192 + q * 8 + 4) = o1;
}

// ---------------------------------------------------------------------------
// Layer-1 MFMA GEMM: h = relu(axb[N x 192] @ Wcat^T + b1), h bf16 [N x 96].
// ---------------------------------------------------------------------------
__global__ __launch_bounds__(256) void l1_mfma_kernel(const unsigned short* __restrict__ axb,
                                                      const unsigned short* __restrict__ wb,
                                                      const float* __restrict__ bias,
                                                      unsigned short* __restrict__ h,
                                                      int N) {
    int wave = threadIdx.x >> 6, lane = threadIdx.x & 63;
    int nbase = blockIdx.x * 128 + wave * 32;
    int mrow = lane & 15, quad = lane >> 4;
    float4v acc[2][6] = {};
    const short8* W = (const short8*)wb;

    #pragma unroll
    for (int kc = 0; kc < 6; ++kc) {
        short8 a0 = *(const short8*)(axb + (size_t)(nbase + mrow)      * 192 + kc * 32 + quad * 8);
        short8 a1 = *(const short8*)(axb + (size_t)(nbase + 16 + mrow) * 192 + kc * 32 + quad * 8);
        #pragma unroll
        for (int jt = 0; jt < 6; ++jt) {
            short8 b = W[(kc * 6 + jt) * 64 + lane];
            acc[0][jt] = __builtin_amdgcn_mfma_f32_16x16x32_bf16(a0, b, acc[0][jt], 0, 0, 0);
            acc[1][jt] = __builtin_amdgcn_mfma_f32_16x16x32_bf16(a1, b, acc[1][jt], 0, 0, 0);
        }
    }

    #pragma unroll
    for (int jt = 0; jt < 6; ++jt) {
        int j = jt * 16 + mrow;
        float bj = bias[j];
        #pragma unroll
        for (int mt = 0; mt < 2; ++mt) {
            #pragma unroll
            for (int r = 0; r < 4; ++r) {
                int node = nbase + mt * 16 + quad * 4 + r;
                if (node < N)
                    h[(size_t)node * 96 + j] = f2bf(fmaxf(acc[mt][jt][r] + bj, 0.f));
            }
        }
    }
}

// ---------------------------------------------------------------------------
// Layer-2 projection MFMA: [pl|pr] = h[N x 96] @ W2cat^T (80 outputs).
// pl bf16 with row stride 64 (one 128B line per row); pr fp32.
// ---------------------------------------------------------------------------
__global__ __launch_bounds__(256) void proj2_mfma_kernel(const unsigned short* __restrict__ h,
                                                         const unsigned short* __restrict__ wb,
                                                         unsigned short* __restrict__ pl,
                                                         float* __restrict__ pr,
                                                         int N) {
    int wave = threadIdx.x >> 6, lane = threadIdx.x & 63;
    int nbase = blockIdx.x * 128 + wave * 32;
    int mrow = lane & 15, quad = lane >> 4;
    float4v acc[2][5] = {};
    const short8* W = (const short8*)wb;

    #pragma unroll
    for (int kc = 0; kc < 3; ++kc) {
        short8 a0 = *(const short8*)(h + (size_t)(nbase + mrow)      * 96 + kc * 32 + quad * 8);
        short8 a1 = *(const short8*)(h + (size_t)(nbase + 16 + mrow) * 96 + kc * 32 + quad * 8);
        #pragma unroll
        for (int jt = 0; jt < 5; ++jt) {
            short8 b = W[(kc * 5 + jt) * 64 + lane];
            acc[0][jt] = __builtin_amdgcn_mfma_f32_16x16x32_bf16(a0, b, acc[0][jt], 0, 0, 0);
            acc[1][jt] = __builtin_amdgcn_mfma_f32_16x16x32_bf16(a1, b, acc[1][jt], 0, 0, 0);
        }
    }

    #pragma unroll
    for (int jt = 0; jt < 5; ++jt) {
        int j = jt * 16 + mrow;
        #pragma unroll
        for (int mt = 0; mt < 2; ++mt) {
            #pragma unroll
            for (int r = 0; r < 4; ++r) {
                int node = nbase + mt * 16 + quad * 4 + r;
                if (node < N) {
                    float v = acc[mt][jt][r];
                    if (j < 40) pl[(size_t)node * 64 + j] = f2bf(v);
                    else        pr[(size_t)node * 40 + (j - 40)] = v;
                }
            }
        }
    }
}

// ---------------------------------------------------------------------------
// Final: logits = mean_{src}(pl[src]) + b2 + pr[n]; log_softmax. One wave
// per node, lanes < 40 active, 4-edge unroll, shuffle reductions.
// ---------------------------------------------------------------------------
__global__ __launch_bounds__(256) void final_kernel(const unsigned short* __restrict__ pl,
                                                    const float* __restrict__ pr,
                                                    const float* __restrict__ b,
                                                    const int* __restrict__ rp,
                                                    const unsigned short* __restrict__ col,
                                                    float* __restrict__ out, int N) {
    int w    = threadIdx.x >> 6;
    int lane = threadIdx.x & 63;
    int n = blockIdx.x * 4 + w;
    if (n >= N) return;
    int s = rp[n], e = rp[n + 1];
    bool act = lane < NCLASS;
    float acc = 0.f;
    int i = s;
    for (; i + 3 < e; i += 4) {
        int c0 = col[i], c1 = col[i+1], c2 = col[i+2], c3 = col[i+3];
        if (act) acc += bf2f(pl[(size_t)c0 * 64 + lane]) + bf2f(pl[(size_t)c1 * 64 + lane])
                      + bf2f(pl[(size_t)c2 * 64 + lane]) + bf2f(pl[(size_t)c3 * 64 + lane]);
    }
    for (; i < e; ++i) {
        int c = col[i];
        if (act) acc += bf2f(pl[(size_t)c * 64 + lane]);
    }
    float v = -INFINITY;
    if (act) {
        int deg = e - s;
        float inv = 1.0f / (float)(deg > 1 ? deg : 1);
        v = acc * inv + b[lane] + pr[(size_t)n * 40 + lane];
    }
    float m = v;
    #pragma unroll
    for (int off = 32; off >= 1; off >>= 1) m = fmaxf(m, __shfl_xor(m, off));
    float ex = act ? __expf(v - m) : 0.f;
    float ssum = ex;
    #pragma unroll
    for (int off = 32; off >= 1; off >>= 1) ssum += __shfl_xor(ssum, off);
    if (act) out[(size_t)n * 40 + lane] = v - m - __logf(ssum);
}

// ---------------------------------------------------------------------------
// Host launcher
// ---------------------------------------------------------------------------
extern "C" void kernel_launch(void* const* d_in, const int* in_sizes, int n_in,
                              void* d_out, int out_size, void* d_ws, size_t ws_size,
                              hipStream_t stream) {
    const float* x   = (const float*)d_in[0];
    const int*   ei  = (const int*)  d_in[1];
    const float* W1l = (const float*)d_in[2];
    const float* b1  = (const float*)d_in[3];
    const float* W1r = (const float*)d_in[4];
    const float* W2l = (const float*)d_in[5];
    const float* b2  = (const float*)d_in[6];
    const float* W2r = (const float*)d_in[7];
    float* out = (float*)d_out;

    const int N = in_sizes[0] / 96;      // 50000 (must be < 65536 for u16 col)
    const int E = in_sizes[1] / 2;       // 800000
    const int nbucket = (N + 127) >> 7;  // 391
    const int nbin = (E + EPB - 1) / EPB;// 196 (must be <= 256)
    const int NB   = (N + 127) / 128;    // MFMA blocks (128 nodes each)
    const int NP2  = NB * 128;           // padded rows

    // Workspace layout (all offsets 256-aligned).
    auto al = [](size_t v) { return (v + 255) & ~(size_t)255; };
    char* ws = (char*)d_ws;
    size_t o = 0;
    int* histT   = (int*)(ws + o); o = al(o + (size_t)MAXB * 256 * 4);
    int* gbh     = (int*)(ws + o); o = al(o + (size_t)MAXB * 4);
    int* gbase   = (int*)(ws + o); o = al(o + (size_t)(MAXB + 1) * 4);
    int* rp      = (int*)(ws + o); o = al(o + (size_t)(N + 1) * 4);
    unsigned int*   tmp = (unsigned int*)(ws + o);   o = al(o + (size_t)E * 4);
    unsigned short* col = (unsigned short*)(ws + o); o = al(o + (size_t)E * 2);
    size_t off_axb = o;
    unsigned short* axb = (unsigned short*)(ws + o); o = al(o + (size_t)NP2 * 192 * 2);
    unsigned short* h   = (unsigned short*)(ws + o); o = al(o + (size_t)NP2 * 96 * 2);
    unsigned short* wb1 = (unsigned short*)(ws + o); o = al(o + 36 * 64 * 8 * 2);
    unsigned short* wb2 = (unsigned short*)(ws + o); o = al(o + 15 * 64 * 8 * 2);
    unsigned short* pl  = (unsigned short*)(ws + o); o = al(o + (size_t)NP2 * 64 * 2);
    // pr overlays axb (axb dead after l1_mfma; proj2/final run later). 8MB <= 19.2MB.
    float* pr = (float*)(ws + off_axb);

    // CSR build: per-block histograms -> scans -> deterministic single-pass bin.
    bhist_kernel<<<nbin, 256, 0, stream>>>(ei, histT, E, nbucket, nbin);
    bsum_kernel <<<nbucket, 256, 0, stream>>>(histT, gbh, nbin);
    bscan_kernel<<<1, 512, 0, stream>>>(gbh, gbase, rp, N, E, nbucket);
    bin_kernel  <<<nbin, 256, 0, stream>>>(ei, gbase, histT, tmp, E, nbucket, nbin);
    bucket_csr_kernel<<<nbucket, 256, 0, stream>>>(tmp, gbase, rp, col, N);

    // bf16 conversions.
    xconv_kernel<<<(N * 24 + 255) / 256, 256, 0, stream>>>((const float4*)x, axb, N);
    wconv_kernel<<<13, 256, 0, stream>>>(W1l, W1r, W2l, W2r, wb1, wb2);

    // Layer 1: gather-mean (bf16) then MFMA GEMM.
    agg1_kernel   <<<(N * 12 + 255) / 256, 256, 0, stream>>>(rp, col, axb, N);
    l1_mfma_kernel<<<NB, 256, 0, stream>>>(axb, wb1, b1, h, N);

    // Layer 2: project first (mean commutes with linear), aggregate 40-dim.
    proj2_mfma_kernel<<<NB, 256, 0, stream>>>(h, wb2, pl, pr, N);
    final_kernel<<<(N + 3) / 4, 256, 0, stream>>>(pl, pr, b2, rp, col, out, N);
}